// Round 2
// baseline (297.284 us; speedup 1.0000x reference)
//
#include <hip/hip_runtime.h>

// CTC loss forward, T=1024, B=128, C=256, S=128, L=2S+1=257.
// One wave (64 lanes) per batch. Lane l owns odd states O[2l],O[2l+1]
// (labels y[2l],y[2l+1]) and blank states E[2l],E[2l+1]; E[128] replicated
// wave-wide. Exp-domain recursion in FP64 (708-nat range below the running
// max vs ~400-nat worst-case state spread; f32's 87 nats dropped ~10% of
// samples in R1). Power-of-2 renorm every 8 steps (exact); probabilities
// exponentiated in f32 (__expf) then widened. 8-deep register prefetch of
// the 3 gathered log-probs per step hides ~900-cyc HBM latency.

#define PF 8          // prefetch depth (steps ahead)
#define CTC_C 256     // number of classes (fixed by the problem)

__device__ __forceinline__ void renorm(double& Oa, double& Ob, double& Ea,
                                       double& Eb, double& E128, double& logC) {
  double m = fmax(fmax(Oa, Ob), fmax(Ea, Eb));
#pragma unroll
  for (int off = 32; off > 0; off >>= 1)
    m = fmax(m, __shfl_xor(m, off));
  m = fmax(m, E128);
  if (m > 0.) {
    long long bits = __double_as_longlong(m);
    int eb = (int)((bits >> 52) & 0x7ff);        // biased exponent
    int e = eb - 1022;                           // m = f*2^e, f in [0.5,1)
    double s = __longlong_as_double((long long)(2045 - eb) << 52); // 2^-e exact
    Oa *= s; Ob *= s; Ea *= s; Eb *= s; E128 *= s;
    logC += (double)e * 0.6931471805599453;
  }
}

__global__ __launch_bounds__(64)
void ctc_fwd(const float* __restrict__ lp, const int* __restrict__ y,
             const int* __restrict__ ilen, const int* __restrict__ tlen,
             float* __restrict__ out, int T, int B, int S) {
  const int b = blockIdx.x;
  const int l = threadIdx.x;            // 0..63
  const long rowstride = (long)B * CTC_C;   // floats between row t and t+1

  const int len = ilen[b];              // input length, steps t=1..len-1
  const int tl  = tlen[b];              // target length

  // Per-lane labels: j = 2l and 2l+1
  const int ya = y[(size_t)b * S + 2 * l];
  const int yb = y[(size_t)b * S + 2 * l + 1];
  const int yprev = __shfl_up(yb, 1);   // y[2l-1] (garbage on lane 0, masked)
  const bool skipA = (l > 0) && (ya != yprev); // skip into O[2l]
  const bool skipB = (yb != ya);                // skip into O[2l+1]

  // Init (t=0): alpha[0]=lp0[blank], alpha[1]=lp0[y0]; others 0 (== exp(NEG))
  const float* row0 = lp + (size_t)b * CTC_C;
  const int y0 = y[(size_t)b * S];
  double Ea = (l == 0) ? (double)__expf(row0[0])  : 0.;  // E[2l]
  double Oa = (l == 0) ? (double)__expf(row0[y0]) : 0.;  // O[2l]
  double Eb = 0., Ob = 0., E128 = 0.;
  double logC = 0.;

  // Prefetch buffers: 3 gathered values per step, PF steps deep
  float pA[PF], pB[PF], pQ[PF];
#pragma unroll
  for (int d = 0; d < PF; ++d) {
    int t = 1 + d; t = (t < T) ? t : (T - 1);
    const float* r = lp + (size_t)t * rowstride + (size_t)b * CTC_C;
    pA[d] = r[ya]; pB[d] = r[yb]; pQ[d] = r[0];
  }

  const int nsteps = len - 1;           // steps t = 1..nsteps
  const int nchunks = nsteps / PF;
  int t0 = 1;

  for (int c = 0; c < nchunks; ++c) {
#pragma unroll
    for (int d = 0; d < PF; ++d) {
      const int t = t0 + d;
      double pa = (double)__expf(pA[d]);
      double pb = (double)__expf(pB[d]);
      double pq = (double)__expf(pQ[d]);
      // refill slot d with row t+PF (clamped; unused rows harmless)
      int tn = t + PF; tn = (tn < T) ? tn : (T - 1);
      const float* r = lp + (size_t)tn * rowstride + (size_t)b * CTC_C;
      pA[d] = r[ya]; pB[d] = r[yb]; pQ[d] = r[0];

      double Opm1 = __shfl_up(Ob, 1);          // O[2l-1]
      Opm1 = (l == 0) ? 0. : Opm1;
      double O127 = __shfl(Ob, 63);            // O[127] broadcast

      double nOa = (Oa + Ea + (skipA ? Opm1 : 0.)) * pa;
      double nOb = (Ob + Eb + (skipB ? Oa   : 0.)) * pb;
      double nEa = (Ea + Opm1) * pq;
      double nEb = (Eb + Oa) * pq;
      E128 = (E128 + O127) * pq;
      Oa = nOa; Ob = nOb; Ea = nEa; Eb = nEb;

      if ((d & 7) == 7) renorm(Oa, Ob, Ea, Eb, E128, logC);
    }
    t0 += PF;
  }

  // tail: up to PF-1 remaining steps (wave-uniform predicate; shuffles safe)
#pragma unroll
  for (int d = 0; d < PF; ++d) {
    const int t = t0 + d;
    if (t <= nsteps) {
      double pa = (double)__expf(pA[d]);
      double pb = (double)__expf(pB[d]);
      double pq = (double)__expf(pQ[d]);
      double Opm1 = __shfl_up(Ob, 1);
      Opm1 = (l == 0) ? 0. : Opm1;
      double O127 = __shfl(Ob, 63);
      double nOa = (Oa + Ea + (skipA ? Opm1 : 0.)) * pa;
      double nOb = (Ob + Eb + (skipB ? Oa   : 0.)) * pb;
      double nEa = (Ea + Opm1) * pq;
      double nEb = (Eb + Oa) * pq;
      E128 = (E128 + O127) * pq;
      Oa = nOa; Ob = nOb; Ea = nEa; Eb = nEb;
      if ((d & 7) == 7) renorm(Oa, Ob, Ea, Eb, E128, logC);
    }
  }

  // Final: ll = logC + log(alpha_exp[2*tl] + alpha_exp[2*tl-1])
  double vEa = __shfl(Ea, (tl >> 1) & 63);
  double vEb = __shfl(Eb, (tl >> 1) & 63);
  double vhi = (tl == S) ? E128 : ((tl & 1) ? vEb : vEa);
  int s2 = tl - 1;
  double vOa = __shfl(Oa, (s2 >> 1) & 63);
  double vOb = __shfl(Ob, (s2 >> 1) & 63);
  double vlo = (s2 & 1) ? vOb : vOa;

  double sum = vhi + vlo;
  double loss;
  if (sum > 0.) {
    loss = -(logC + log(sum));          // log in f64: sum can be ~e^-400
  } else {
    loss = 1e30;                        // -inf likelihood
  }
  if (!(loss < 5.0e8)) loss = 0.;       // zero_infinity (catches inf/NaN)
  float contrib = (float)(loss / (double)tl / (double)B);
  if (l == 0) atomicAdd(out, contrib);
}

extern "C" void kernel_launch(void* const* d_in, const int* in_sizes, int n_in,
                              void* d_out, int out_size, void* d_ws, size_t ws_size,
                              hipStream_t stream) {
  const float* lp   = (const float*)d_in[0];
  const int*   yy   = (const int*)d_in[1];
  const int*   ilen = (const int*)d_in[2];
  const int*   tlen = (const int*)d_in[3];
  float* out = (float*)d_out;

  int B = in_sizes[2];
  int S = in_sizes[1] / B;
  int T = in_sizes[0] / (B * CTC_C);

  hipMemsetAsync(out, 0, sizeof(float), stream);
  ctc_fwd<<<B, 64, 0, stream>>>(lp, yy, ilen, tlen, out, T, B, S);
}